// Round 1
// baseline (273.587 us; speedup 1.0000x reference)
//
#include <hip/hip_runtime.h>
#include <hip/hip_bf16.h>
#include <math.h>

// Problem constants (from reference setup_inputs)
#define NB   4096   // batch
#define NH   200    // history length
#define HALF 64     // half embed dim
#define ND   128    // embed dim
#define NHID 64     // hidden

// One block per batch element b. Thread tid==j computes one history row:
//   inp[j,:] = concat(W_hist[hist], W_reg[hreg]) * t      (t in LDS)
//   r1 = relu(inp @ W1 + b1); logit = r1 . W2; s_j = sum(inp)
// then block-reduce E = sum_j exp(logit_j)*mask, P = sum_j exp*mask*s_j,
//   out[b] = sigmoid(P / sqrt(E))        (BETA = 0.5)
__global__ __launch_bounds__(256) void nais_fused(
    const int*   __restrict__ history,
    const int*   __restrict__ target,
    const int*   __restrict__ history_region,
    const int*   __restrict__ target_region,
    const float* __restrict__ W_hist,
    const float* __restrict__ W_tgt,
    const float* __restrict__ W_reg,
    const float* __restrict__ W1,
    const float* __restrict__ b1,
    const float* __restrict__ W2,
    float*       __restrict__ out)
{
    __shared__ __align__(16) float t_lds[ND];
    __shared__ float red_e[4];
    __shared__ float red_p[4];

    const int b   = blockIdx.x;
    const int tid = threadIdx.x;

    const int tgt = target[b];

    // stage t = concat(W_tgt[tgt], W_reg[treg]) into LDS
    if (tid < 64) {
        t_lds[tid] = W_tgt[tgt * 64 + tid];
    } else if (tid < 128) {
        const int treg = target_region[b];
        t_lds[tid] = W_reg[treg * 64 + (tid - 64)];
    }
    __syncthreads();

    float e = 0.0f;   // exp(logit)*mask for this j
    float p = 0.0f;   // e * s_j

    if (tid < NH) {
        const int j    = tid;
        const int hist = history[b * NH + j];
        const int hreg = history_region[b * NH + j];
        const float* __restrict__ hrow = W_hist + hist * 64;
        const float* __restrict__ rrow = W_reg  + hreg * 64;

        float acc[NHID];
        #pragma unroll
        for (int k = 0; k < NHID; ++k) acc[k] = b1[k];

        float s = 0.0f;

        // phase 1: d in [0,64) -> W_hist half
        #pragma unroll 1
        for (int d = 0; d < 64; d += 4) {
            const float4 h4 = *(const float4*)(hrow + d);
            const float4 t4 = *(const float4*)(t_lds + d);
            float iv[4];
            iv[0] = h4.x * t4.x; iv[1] = h4.y * t4.y;
            iv[2] = h4.z * t4.z; iv[3] = h4.w * t4.w;
            #pragma unroll
            for (int dd = 0; dd < 4; ++dd) {
                s += iv[dd];
                const float* __restrict__ wrow = W1 + (d + dd) * NHID; // wave-uniform -> s_load
                #pragma unroll
                for (int k = 0; k < NHID; ++k)
                    acc[k] = fmaf(iv[dd], wrow[k], acc[k]);
            }
        }
        // phase 2: d in [64,128) -> W_reg half
        #pragma unroll 1
        for (int d = 0; d < 64; d += 4) {
            const float4 h4 = *(const float4*)(rrow + d);
            const float4 t4 = *(const float4*)(t_lds + 64 + d);
            float iv[4];
            iv[0] = h4.x * t4.x; iv[1] = h4.y * t4.y;
            iv[2] = h4.z * t4.z; iv[3] = h4.w * t4.w;
            #pragma unroll
            for (int dd = 0; dd < 4; ++dd) {
                s += iv[dd];
                const float* __restrict__ wrow = W1 + (64 + d + dd) * NHID;
                #pragma unroll
                for (int k = 0; k < NHID; ++k)
                    acc[k] = fmaf(iv[dd], wrow[k], acc[k]);
            }
        }

        float logit = 0.0f;
        #pragma unroll
        for (int k = 0; k < NHID; ++k)
            logit = fmaf(fmaxf(acc[k], 0.0f), W2[k], logit);

        const float ex = (hist != tgt) ? expf(logit) : 0.0f;
        e = ex;
        p = ex * s;
    }

    // 64-lane wave reduction (wave = 64 on CDNA)
    #pragma unroll
    for (int off = 32; off > 0; off >>= 1) {
        e += __shfl_down(e, off);
        p += __shfl_down(p, off);
    }
    const int wave = tid >> 6;
    const int lane = tid & 63;
    if (lane == 0) { red_e[wave] = e; red_p[wave] = p; }
    __syncthreads();

    if (tid == 0) {
        const float E = red_e[0] + red_e[1] + red_e[2] + red_e[3];
        const float P = red_p[0] + red_p[1] + red_p[2] + red_p[3];
        const float pred = P / sqrtf(E);     // exp_sum ** 0.5
        out[b] = 1.0f / (1.0f + expf(-pred));
    }
}

extern "C" void kernel_launch(void* const* d_in, const int* in_sizes, int n_in,
                              void* d_out, int out_size, void* d_ws, size_t ws_size,
                              hipStream_t stream) {
    const int*   history        = (const int*)  d_in[0];
    const int*   target         = (const int*)  d_in[1];
    const int*   history_region = (const int*)  d_in[2];
    const int*   target_region  = (const int*)  d_in[3];
    const float* W_hist         = (const float*)d_in[4];
    const float* W_tgt          = (const float*)d_in[5];
    const float* W_reg          = (const float*)d_in[6];
    const float* W1             = (const float*)d_in[7];
    const float* b1             = (const float*)d_in[8];
    const float* W2             = (const float*)d_in[9];
    float* out = (float*)d_out;

    nais_fused<<<NB, 256, 0, stream>>>(history, target, history_region, target_region,
                                       W_hist, W_tgt, W_reg, W1, b1, W2, out);
}

// Round 2
// 245.014 us; speedup vs baseline: 1.1166x; 1.1166x over previous
//
#include <hip/hip_runtime.h>
#include <math.h>

// Problem constants (from reference setup_inputs)
#define NB   4096   // batch
#define NH   200    // history length
#define NHID 64     // hidden
#define BK   136    // padded row stride in bf16 elems (272 B: 16B-aligned rows, 2-way-max bank conflicts)

typedef __attribute__((ext_vector_type(8))) short short8;  // 8 bf16 = 4 VGPRs (MFMA A/B frag)
typedef __attribute__((ext_vector_type(4))) float f32x4;   // MFMA C/D frag

// fp32 -> bf16 round-to-nearest-even
__device__ __forceinline__ unsigned short f2bf(float x) {
    union { float f; unsigned u; } v; v.f = x;
    unsigned r = v.u + 0x7FFF + ((v.u >> 16) & 1);
    return (unsigned short)(r >> 16);
}

// One block per batch element b.
//   X[j,:] = concat(W_hist[hist_j], W_reg[hreg_j]) * t   (bf16 in LDS, 2 chunks of <=112 rows)
//   [R | s] = X @ [W1 | ones]  via mfma_f32_16x16x32_bf16 (5 N-tiles: 4x W1 + ones col)
//   logit_j = relu(R_j + b1) . W2  (epilogue, 16-lane shfl_xor reduce)
//   out[b]  = sigmoid( sum_j e_j s_j / sqrt(sum_j e_j) ),  e_j = exp(logit_j)*[hist_j != tgt]
__global__ __launch_bounds__(256, 2) void nais_mfma(
    const int*   __restrict__ history,
    const int*   __restrict__ target,
    const int*   __restrict__ history_region,
    const int*   __restrict__ target_region,
    const float* __restrict__ W_hist,
    const float* __restrict__ W_tgt,
    const float* __restrict__ W_reg,
    const float* __restrict__ W1,
    const float* __restrict__ b1,
    const float* __restrict__ W2,
    float*       __restrict__ out)
{
    __shared__ int hist_lds[NH];
    __shared__ int hreg_lds[NH];
    __shared__ __align__(16) float t_lds[128];
    __shared__ float w2_lds[64];
    __shared__ float b1_lds[64];
    __shared__ __align__(16) unsigned short Xs[112 * BK];  // bf16 X chunk (<=7 M-tiles)
    __shared__ __align__(16) unsigned short Bs[80 * BK];   // bf16 [W1 | ones | 0] transposed: [n][k]
    __shared__ float logit_lds[208];
    __shared__ float s_lds[208];
    __shared__ float red_e[4];
    __shared__ float red_p[4];

    const int b   = blockIdx.x;
    const int tid = threadIdx.x;
    const int tgt = target[b];

    // ---- stage indices, t, W2, b1 ----
    if (tid < NH) {
        hist_lds[tid] = history[b * NH + tid];
        hreg_lds[tid] = history_region[b * NH + tid];
    }
    if (tid < 64) {
        t_lds[tid]  = W_tgt[(size_t)tgt * 64 + tid];
        w2_lds[tid] = W2[tid];
        b1_lds[tid] = b1[tid];
    } else if (tid < 128) {
        t_lds[tid] = W_reg[(size_t)target_region[b] * 64 + (tid - 64)];
    }
    // ---- stage B = [W1 | ones | 0]^T as bf16, [n][k] (contiguous in k) ----
    for (int i = tid; i < 128 * 64; i += 256) {       // coalesced W1 read
        const int k = i >> 6, n = i & 63;
        Bs[n * BK + k] = f2bf(W1[i]);
    }
    for (int i = tid; i < 16 * 128; i += 256) {       // cols 64..79: ones column + zero pad
        const int n = 64 + (i >> 7), k = i & 127;
        Bs[n * BK + k] = (n == 64) ? f2bf(1.0f) : (unsigned short)0;
    }
    __syncthreads();

    const int lane = tid & 63, wv = tid >> 6;
    const int l15  = lane & 15, quad = lane >> 4;

    // ---- hoist all B fragments into registers (constant across tiles/chunks): 20 x short8 = 80 VGPRs ----
    short8 bfrag[5][4];
    #pragma unroll
    for (int nt = 0; nt < 5; ++nt)
        #pragma unroll
        for (int ks = 0; ks < 4; ++ks)
            bfrag[nt][ks] = *reinterpret_cast<const short8*>(
                &Bs[(nt * 16 + l15) * BK + ks * 32 + quad * 8]);

    float w2v[4], b1v[4];
    #pragma unroll
    for (int nt = 0; nt < 4; ++nt) {
        w2v[nt] = w2_lds[nt * 16 + l15];   // col = nt*16 + (lane&15), fixed per lane
        b1v[nt] = b1_lds[nt * 16 + l15];
    }

    // ---- two M-chunks: rows [0,112) and [112,208); valid rows < 200 ----
    for (int c = 0; c < 2; ++c) {
        const int base   = c * 112;
        const int nrows  = c ? 96 : 112;
        const int ntiles = c ? 6  : 7;

        // formation: X[rl][0:128] = gather-row * t, bf16
        for (int i = tid; i < nrows * 32; i += 256) {
            const int rl = i >> 5, seg = i & 31;
            const int j  = base + rl;
            if (j < NH) {
                const float* src; int tseg;
                if (seg < 16) { src = W_hist + (size_t)hist_lds[j] * 64 + seg * 4;        tseg = seg * 4; }
                else          { src = W_reg  + (size_t)hreg_lds[j] * 64 + (seg - 16) * 4; tseg = 64 + (seg - 16) * 4; }
                const float4 v  = *(const float4*)src;
                const float4 tv = *(const float4*)(t_lds + tseg);
                ushort4 o;
                o.x = f2bf(v.x * tv.x); o.y = f2bf(v.y * tv.y);
                o.z = f2bf(v.z * tv.z); o.w = f2bf(v.w * tv.w);
                *reinterpret_cast<ushort4*>(&Xs[rl * BK + tseg]) = o;
            }
            // pad rows (j>=200) left as garbage: MFMA rows are independent, never read back
        }
        __syncthreads();

        // MFMA + epilogue: wave wv handles M-tiles wv, wv+4, ...
        for (int tl = wv; tl < ntiles; tl += 4) {
            f32x4 acc[5];
            #pragma unroll
            for (int nt = 0; nt < 5; ++nt) acc[nt] = (f32x4){0.f, 0.f, 0.f, 0.f};
            #pragma unroll
            for (int ks = 0; ks < 4; ++ks) {
                const short8 a = *reinterpret_cast<const short8*>(
                    &Xs[(tl * 16 + l15) * BK + ks * 32 + quad * 8]);
                #pragma unroll
                for (int nt = 0; nt < 5; ++nt)
                    acc[nt] = __builtin_amdgcn_mfma_f32_16x16x32_bf16(a, bfrag[nt][ks], acc[nt], 0, 0, 0);
            }
            // epilogue: logit partial over this lane's 4 cols (c = nt*16+l15), rows = quad*4+r
            float part[4] = {0.f, 0.f, 0.f, 0.f};
            #pragma unroll
            for (int nt = 0; nt < 4; ++nt)
                #pragma unroll
                for (int r = 0; r < 4; ++r)
                    part[r] += fmaxf(acc[nt][r] + b1v[nt], 0.f) * w2v[nt];
            #pragma unroll
            for (int r = 0; r < 4; ++r) {
                part[r] += __shfl_xor(part[r], 1);
                part[r] += __shfl_xor(part[r], 2);
                part[r] += __shfl_xor(part[r], 4);
                part[r] += __shfl_xor(part[r], 8);
            }
            if (l15 == 0) {   // this lane's ones-col (64 + l15 == 64) holds s_j; part[] fully reduced
                const int jg = base + tl * 16 + quad * 4;
                #pragma unroll
                for (int r = 0; r < 4; ++r) {
                    logit_lds[jg + r] = part[r];
                    s_lds[jg + r]     = acc[4][r];
                }
            }
        }
        __syncthreads();   // protects X overwrite (c=0) and logit/s reads (c=1)
    }

    // ---- beta-softmax block reduction ----
    float e = 0.f, p = 0.f;
    if (tid < NH) {
        const float ex = (hist_lds[tid] != tgt) ? expf(logit_lds[tid]) : 0.f;
        e = ex;
        p = ex * s_lds[tid];
    }
    #pragma unroll
    for (int off = 32; off > 0; off >>= 1) {
        e += __shfl_down(e, off);
        p += __shfl_down(p, off);
    }
    if (lane == 0) { red_e[wv] = e; red_p[wv] = p; }
    __syncthreads();
    if (tid == 0) {
        const float E = red_e[0] + red_e[1] + red_e[2] + red_e[3];
        const float P = red_p[0] + red_p[1] + red_p[2] + red_p[3];
        const float pred = P / sqrtf(E);      // exp_sum ** 0.5 (BETA = 0.5)
        out[b] = 1.f / (1.f + expf(-pred));
    }
}

extern "C" void kernel_launch(void* const* d_in, const int* in_sizes, int n_in,
                              void* d_out, int out_size, void* d_ws, size_t ws_size,
                              hipStream_t stream) {
    const int*   history        = (const int*)  d_in[0];
    const int*   target         = (const int*)  d_in[1];
    const int*   history_region = (const int*)  d_in[2];
    const int*   target_region  = (const int*)  d_in[3];
    const float* W_hist         = (const float*)d_in[4];
    const float* W_tgt          = (const float*)d_in[5];
    const float* W_reg          = (const float*)d_in[6];
    const float* W1             = (const float*)d_in[7];
    const float* b1             = (const float*)d_in[8];
    const float* W2             = (const float*)d_in[9];
    float* out = (float*)d_out;

    nais_mfma<<<NB, 256, 0, stream>>>(history, target, history_region, target_region,
                                      W_hist, W_tgt, W_reg, W1, b1, W2, out);
}

// Round 3
// 200.693 us; speedup vs baseline: 1.3632x; 1.2208x over previous
//
#include <hip/hip_runtime.h>
#include <math.h>

// Problem constants (from reference setup_inputs)
#define NB   4096   // batch
#define NH   200    // history length
#define NHID 64     // hidden
#define BK   136    // padded row stride for Bs (bf16 elems; 272B rows -> 2-way LDS aliasing = free)

typedef __attribute__((ext_vector_type(8))) short short8;  // 8 bf16 = 4 VGPRs (MFMA A/B frag)
typedef __attribute__((ext_vector_type(4))) float f32x4;   // MFMA C/D frag

// fp32 -> bf16 round-to-nearest-even
__device__ __forceinline__ unsigned short f2bf(float x) {
    union { float f; unsigned u; } v; v.f = x;
    unsigned r = v.u + 0x7FFF + ((v.u >> 16) & 1);
    return (unsigned short)(r >> 16);
}

// One block per batch element b. A-fragments of X = (gather * t) are formed
// DIRECTLY in registers from global gathers (no X LDS staging):
//   lane(quad,l15) of M-tile tl holds row j=tl*16+l15, cols ks*32+quad*8+(0..7).
// [R | s] = X @ [W1 | ones] via mfma_f32_16x16x32_bf16; epilogue relu.W2 per row;
// out[b] = sigmoid( sum_j e_j s_j / sqrt(sum_j e_j) ), e_j = exp(logit_j)*[hist_j!=tgt].
__global__ __launch_bounds__(256, 3) void nais_mfma2(
    const int*   __restrict__ history,
    const int*   __restrict__ target,
    const int*   __restrict__ history_region,
    const int*   __restrict__ target_region,
    const float* __restrict__ W_hist,
    const float* __restrict__ W_tgt,
    const float* __restrict__ W_reg,
    const float* __restrict__ W1,
    const float* __restrict__ b1,
    const float* __restrict__ W2,
    float*       __restrict__ out)
{
    __shared__ int hist_lds[208];
    __shared__ int hreg_lds[208];
    __shared__ __align__(16) float t_lds[128];
    __shared__ float w2_lds[64];
    __shared__ float b1_lds[64];
    __shared__ __align__(16) unsigned short Bs[80 * BK]; // [W1 | ones | 0]^T as bf16, [n][k]
    __shared__ float logit_lds[208];
    __shared__ float s_lds[208];
    __shared__ float red_e[4];
    __shared__ float red_p[4];

    const int b   = blockIdx.x;
    const int tid = threadIdx.x;
    const int tgt = target[b];

    // ---- stage indices (padded to 208 with a duplicate of row 199), t, W2, b1 ----
    if (tid < 208) {
        const int jj = tid < NH ? tid : NH - 1;
        hist_lds[tid] = history[b * NH + jj];
        hreg_lds[tid] = history_region[b * NH + jj];
    }
    if (tid < 64) {
        t_lds[tid]  = W_tgt[(size_t)tgt * 64 + tid];
        w2_lds[tid] = W2[tid];
        b1_lds[tid] = b1[tid];
    } else if (tid < 128) {
        t_lds[tid] = W_reg[(size_t)target_region[b] * 64 + (tid - 64)];
    }
    // ---- stage B = [W1 | ones | 0]^T as bf16, [n][k] contiguous in k ----
    for (int i = tid; i < 128 * 64; i += 256) {       // coalesced W1 read
        const int k = i >> 6, n = i & 63;
        Bs[n * BK + k] = f2bf(W1[i]);
    }
    for (int i = tid; i < 16 * 128; i += 256) {       // cols 64..79: ones column + zero pad
        const int n = 64 + (i >> 7), k = i & 127;
        Bs[n * BK + k] = (n == 64) ? f2bf(1.0f) : (unsigned short)0;
    }
    __syncthreads();

    const int lane = tid & 63, wv = tid >> 6;
    const int l15  = lane & 15, quad = lane >> 4;

    // ---- hoist B fragments (constant across all tiles): 20 x short8 = 80 VGPRs ----
    short8 bfrag[5][4];
    #pragma unroll
    for (int nt = 0; nt < 5; ++nt)
        #pragma unroll
        for (int ks = 0; ks < 4; ++ks)
            bfrag[nt][ks] = *reinterpret_cast<const short8*>(
                &Bs[(nt * 16 + l15) * BK + ks * 32 + quad * 8]);

    float w2v[4], b1v[4];
    #pragma unroll
    for (int nt = 0; nt < 4; ++nt) {
        w2v[nt] = w2_lds[nt * 16 + l15];   // this lane's output col = nt*16 + l15
        b1v[nt] = b1_lds[nt * 16 + l15];
    }

    // ---- 13 M-tiles (208 rows), wave wv handles tl = wv, wv+4, ... ----
    #pragma unroll 1
    for (int tl = wv; tl < 13; tl += 4) {
        const int j = tl * 16 + l15;                     // this lane's row
        const float* rowh = W_hist + (size_t)hist_lds[j] * 64 + quad * 8;
        const float* rowr = W_reg  + (size_t)hreg_lds[j] * 64 + quad * 8;

        // issue all 8 gather loads up front (ILP); per row the 4 quads cover
        // each 128B cache line exactly -> coalesces like the old staging loop
        float4 va[4][2];
        va[0][0] = *(const float4*)(rowh);      va[0][1] = *(const float4*)(rowh + 4);
        va[1][0] = *(const float4*)(rowh + 32); va[1][1] = *(const float4*)(rowh + 36);
        va[2][0] = *(const float4*)(rowr);      va[2][1] = *(const float4*)(rowr + 4);
        va[3][0] = *(const float4*)(rowr + 32); va[3][1] = *(const float4*)(rowr + 36);

        f32x4 acc[5];
        #pragma unroll
        for (int nt = 0; nt < 5; ++nt) acc[nt] = (f32x4){0.f, 0.f, 0.f, 0.f};

        #pragma unroll
        for (int ks = 0; ks < 4; ++ks) {
            const float4 t4a = *(const float4*)(t_lds + ks * 32 + quad * 8);
            const float4 t4b = *(const float4*)(t_lds + ks * 32 + quad * 8 + 4);
            short8 a;
            a[0] = (short)f2bf(va[ks][0].x * t4a.x);
            a[1] = (short)f2bf(va[ks][0].y * t4a.y);
            a[2] = (short)f2bf(va[ks][0].z * t4a.z);
            a[3] = (short)f2bf(va[ks][0].w * t4a.w);
            a[4] = (short)f2bf(va[ks][1].x * t4b.x);
            a[5] = (short)f2bf(va[ks][1].y * t4b.y);
            a[6] = (short)f2bf(va[ks][1].z * t4b.z);
            a[7] = (short)f2bf(va[ks][1].w * t4b.w);
            #pragma unroll
            for (int nt = 0; nt < 5; ++nt)
                acc[nt] = __builtin_amdgcn_mfma_f32_16x16x32_bf16(a, bfrag[nt][ks], acc[nt], 0, 0, 0);
        }

        // epilogue: logit over this lane's 4 cols; rows = quad*4 + r
        float part[4] = {0.f, 0.f, 0.f, 0.f};
        #pragma unroll
        for (int nt = 0; nt < 4; ++nt)
            #pragma unroll
            for (int r = 0; r < 4; ++r)
                part[r] += fmaxf(acc[nt][r] + b1v[nt], 0.f) * w2v[nt];
        #pragma unroll
        for (int r = 0; r < 4; ++r) {
            part[r] += __shfl_xor(part[r], 1);
            part[r] += __shfl_xor(part[r], 2);
            part[r] += __shfl_xor(part[r], 4);
            part[r] += __shfl_xor(part[r], 8);
        }
        if (l15 == 0) {   // fully-reduced logit; ones-col acc (nt=4) holds s_j
            const int jg = tl * 16 + quad * 4;
            #pragma unroll
            for (int r = 0; r < 4; ++r) {
                logit_lds[jg + r] = part[r];
                s_lds[jg + r]     = acc[4][r];
            }
        }
    }
    __syncthreads();

    // ---- beta-softmax block reduction ----
    float e = 0.f, p = 0.f;
    if (tid < NH) {
        const float ex = (hist_lds[tid] != tgt) ? expf(logit_lds[tid]) : 0.f;
        e = ex;
        p = ex * s_lds[tid];
    }
    #pragma unroll
    for (int off = 32; off > 0; off >>= 1) {
        e += __shfl_down(e, off);
        p += __shfl_down(p, off);
    }
    if (lane == 0) { red_e[wv] = e; red_p[wv] = p; }
    __syncthreads();
    if (tid == 0) {
        const float E = red_e[0] + red_e[1] + red_e[2] + red_e[3];
        const float P = red_p[0] + red_p[1] + red_p[2] + red_p[3];
        const float pred = P / sqrtf(E);      // exp_sum ** 0.5 (BETA = 0.5)
        out[b] = 1.f / (1.f + expf(-pred));
    }
}

extern "C" void kernel_launch(void* const* d_in, const int* in_sizes, int n_in,
                              void* d_out, int out_size, void* d_ws, size_t ws_size,
                              hipStream_t stream) {
    const int*   history        = (const int*)  d_in[0];
    const int*   target         = (const int*)  d_in[1];
    const int*   history_region = (const int*)  d_in[2];
    const int*   target_region  = (const int*)  d_in[3];
    const float* W_hist         = (const float*)d_in[4];
    const float* W_tgt          = (const float*)d_in[5];
    const float* W_reg          = (const float*)d_in[6];
    const float* W1             = (const float*)d_in[7];
    const float* b1             = (const float*)d_in[8];
    const float* W2             = (const float*)d_in[9];
    float* out = (float*)d_out;

    nais_mfma2<<<NB, 256, 0, stream>>>(history, target, history_region, target_region,
                                       W_hist, W_tgt, W_reg, W1, b1, W2, out);
}

// Round 4
// 156.277 us; speedup vs baseline: 1.7507x; 1.2842x over previous
//
#include <hip/hip_runtime.h>
#include <math.h>

// Problem constants (from reference setup_inputs)
#define NB        4096
#define NH        200
#define HIST_ROWS 100000
#define REG_ROWS  1000

typedef __attribute__((ext_vector_type(8))) short short8;  // 8 bf16 = 4 VGPRs (MFMA A/B frag)
typedef __attribute__((ext_vector_type(4))) float f32x4;   // MFMA C/D frag

// fp32 -> bf16 round-to-nearest-even
__device__ __forceinline__ unsigned short f2bf(float x) {
    union { float f; unsigned u; } v; v.f = x;
    unsigned r = v.u + 0x7FFF + ((v.u >> 16) & 1);
    return (unsigned short)(r >> 16);
}

// Prepass: convert W_hist and W_reg to bf16 tables in d_ws (concat layout).
__global__ __launch_bounds__(256) void cvt_tables(
    const float* __restrict__ Wh, const float* __restrict__ Wr,
    unsigned short* __restrict__ dst)
{
    const int total4 = (HIST_ROWS + REG_ROWS) * 64 / 4;   // 1,616,000 float4s
    const int HE4    = HIST_ROWS * 64 / 4;
    for (int i = blockIdx.x * blockDim.x + threadIdx.x; i < total4;
         i += gridDim.x * blockDim.x) {
        const float4 v = (i < HE4) ? ((const float4*)Wh)[i]
                                   : ((const float4*)Wr)[i - HE4];
        ushort4 o;
        o.x = f2bf(v.x); o.y = f2bf(v.y); o.z = f2bf(v.z); o.w = f2bf(v.w);
        ((ushort4*)dst)[i] = o;
    }
}

// One block per batch element b. Algebra: inp@W1 = h@(diag(t)W1), s_j = h_j.t,
// so B' = [t(x)W1 | t | 0] (80 cols) is built once per block and A = raw
// gathered rows (bf16 from prepass tables; no per-row t multiply, no cvt).
// B' lives in LDS in MFMA-fragment order: frag (nt,ks) -> 64 chunks of 16B,
// chunk = quad*16+l15, elem j -> B'[n=nt*16+l15][k=ks*32+quad*8+j].
// Both staging writes (b128, lane-contiguous) and hot reads (b128,
// lane-contiguous) are the canonical conflict-free LDS pattern.
// Each wave owns 4 M-tiles (rows wv*64..wv*64+63) processed TOGETHER per
// ks-step so bf[5] (40 VGPRs, short-lived) is reused 4x -> no giant hoist,
// no spill. acc[4][5] = 80 accumulator regs.
template <bool BT>
__global__ __launch_bounds__(256, 3) void nais_mfma3(
    const int*   __restrict__ history,
    const int*   __restrict__ target,
    const int*   __restrict__ history_region,
    const int*   __restrict__ target_region,
    const float* __restrict__ W_hist,
    const float* __restrict__ W_tgt,
    const float* __restrict__ W_reg,
    const float* __restrict__ W1,
    const float* __restrict__ b1,
    const float* __restrict__ W2,
    const unsigned short* __restrict__ tab,   // bf16 tables (BT path)
    float*       __restrict__ out)
{
    __shared__ int hist_lds[256];
    __shared__ int hreg_lds[256];
    __shared__ __align__(16) float t_lds[128];
    __shared__ __align__(16) unsigned short Bf[20 * 512];   // 20 frags x 64 chunks x 8 bf16
    __shared__ float logit_lds[256];
    __shared__ float s_lds[256];
    __shared__ float red_e[4], red_p[4];

    const int b   = blockIdx.x;
    const int tid = threadIdx.x;
    const int tgt = target[b];

    // ---- stage indices (padded to 256 with dup of row 199) and t ----
    {
        const int jj = tid < NH ? tid : NH - 1;
        hist_lds[tid] = history[b * NH + jj];
        hreg_lds[tid] = history_region[b * NH + jj];
    }
    if (tid < 64) {
        t_lds[tid] = W_tgt[(size_t)tgt * 64 + tid];
    } else if (tid < 128) {
        t_lds[tid] = W_reg[(size_t)target_region[b] * 64 + (tid - 64)];
    }
    __syncthreads();

    // ---- build B' fragments cooperatively: 1280 chunks, 5 per thread ----
    // thread -> (frag, chunk); 8 strided W1 reads (L1-resident, lanes coalesce
    // into 64B segments per j) + t multiply; one conflict-free b128 write.
    #pragma unroll
    for (int v = 0; v < 5; ++v) {
        const int i    = tid + v * 256;
        const int frag = i >> 6;            // nt*4 + ks
        const int c    = i & 63;
        const int nt   = frag >> 2, ks = frag & 3;
        const int q    = c >> 4,    l  = c & 15;
        const int k0   = ks * 32 + q * 8;
        short8 o;
        if (nt < 4) {
            const int n = nt * 16 + l;
            #pragma unroll
            for (int j = 0; j < 8; ++j)
                o[j] = (short)f2bf(W1[(k0 + j) * 64 + n] * t_lds[k0 + j]);
        } else {
            #pragma unroll
            for (int j = 0; j < 8; ++j)
                o[j] = (l == 0) ? (short)f2bf(t_lds[k0 + j]) : (short)0;
        }
        *reinterpret_cast<short8*>(&Bf[i * 8]) = o;
    }
    __syncthreads();

    const int lane = tid & 63, wv = tid >> 6;
    const int l15  = lane & 15, quad = lane >> 4;

    float w2v[4], b1v[4];
    #pragma unroll
    for (int nt = 0; nt < 4; ++nt) {
        w2v[nt] = W2[nt * 16 + l15];    // this lane's output col = nt*16+l15
        b1v[nt] = b1[nt * 16 + l15];
    }

    // ---- this wave's 4 M-tiles: rows wv*64 + tt*16 + l15 ----
    const unsigned short* tabr = tab + (size_t)HIST_ROWS * 64;
    const unsigned short* ph16[4];
    const unsigned short* pr16[4];
    const float*          phf[4];
    const float*          prf[4];
    #pragma unroll
    for (int tt = 0; tt < 4; ++tt) {
        const int j = wv * 64 + tt * 16 + l15;
        const int ih = hist_lds[j], ir = hreg_lds[j];
        if (BT) {
            ph16[tt] = tab  + (size_t)ih * 64 + quad * 8;
            pr16[tt] = tabr + (size_t)ir * 64 + quad * 8;
        } else {
            phf[tt] = W_hist + (size_t)ih * 64 + quad * 8;
            prf[tt] = W_reg  + (size_t)ir * 64 + quad * 8;
        }
    }

    f32x4 acc[4][5];
    #pragma unroll
    for (int tt = 0; tt < 4; ++tt)
        #pragma unroll
        for (int nt = 0; nt < 5; ++nt) acc[tt][nt] = (f32x4){0.f, 0.f, 0.f, 0.f};

    #pragma unroll
    for (int ks = 0; ks < 4; ++ks) {
        // B fragments for this ks (reused by all 4 tiles)
        short8 bf[5];
        #pragma unroll
        for (int nt = 0; nt < 5; ++nt)
            bf[nt] = *reinterpret_cast<const short8*>(&Bf[((nt * 4 + ks) * 64 + quad * 16 + l15) * 8]);

        #pragma unroll
        for (int tt = 0; tt < 4; ++tt) {
            short8 a;
            if (BT) {
                const unsigned short* p = (ks < 2) ? ph16[tt] + (ks & 1) * 32
                                                   : pr16[tt] + (ks & 1) * 32;
                a = *reinterpret_cast<const short8*>(p);
            } else {
                const float* p = (ks < 2) ? phf[tt] + (ks & 1) * 32
                                          : prf[tt] + (ks & 1) * 32;
                const float4 v0 = *(const float4*)(p);
                const float4 v1 = *(const float4*)(p + 4);
                a[0] = (short)f2bf(v0.x); a[1] = (short)f2bf(v0.y);
                a[2] = (short)f2bf(v0.z); a[3] = (short)f2bf(v0.w);
                a[4] = (short)f2bf(v1.x); a[5] = (short)f2bf(v1.y);
                a[6] = (short)f2bf(v1.z); a[7] = (short)f2bf(v1.w);
            }
            #pragma unroll
            for (int nt = 0; nt < 5; ++nt)
                acc[tt][nt] = __builtin_amdgcn_mfma_f32_16x16x32_bf16(a, bf[nt], acc[tt][nt], 0, 0, 0);
        }
    }

    // ---- epilogue per tile: logit = relu(R + b1) . W2 ; s from t-column ----
    #pragma unroll
    for (int tt = 0; tt < 4; ++tt) {
        float part[4] = {0.f, 0.f, 0.f, 0.f};
        #pragma unroll
        for (int nt = 0; nt < 4; ++nt)
            #pragma unroll
            for (int r = 0; r < 4; ++r)
                part[r] += fmaxf(acc[tt][nt][r] + b1v[nt], 0.f) * w2v[nt];
        #pragma unroll
        for (int r = 0; r < 4; ++r) {
            part[r] += __shfl_xor(part[r], 1);
            part[r] += __shfl_xor(part[r], 2);
            part[r] += __shfl_xor(part[r], 4);
            part[r] += __shfl_xor(part[r], 8);
        }
        if (l15 == 0) {     // col 64 of B' is t -> acc[tt][4] holds s_j
            const int jg = wv * 64 + tt * 16 + quad * 4;
            #pragma unroll
            for (int r = 0; r < 4; ++r) {
                logit_lds[jg + r] = part[r];
                s_lds[jg + r]     = acc[tt][4][r];
            }
        }
    }
    __syncthreads();

    // ---- beta-softmax block reduction (rows >= 200 excluded) ----
    float e = 0.f, p = 0.f;
    if (tid < NH) {
        const float ex = (hist_lds[tid] != tgt) ? expf(logit_lds[tid]) : 0.f;
        e = ex;
        p = ex * s_lds[tid];
    }
    #pragma unroll
    for (int off = 32; off > 0; off >>= 1) {
        e += __shfl_down(e, off);
        p += __shfl_down(p, off);
    }
    if (lane == 0) { red_e[wv] = e; red_p[wv] = p; }
    __syncthreads();
    if (tid == 0) {
        const float E = red_e[0] + red_e[1] + red_e[2] + red_e[3];
        const float P = red_p[0] + red_p[1] + red_p[2] + red_p[3];
        const float pred = P / sqrtf(E);      // exp_sum ** 0.5 (BETA = 0.5)
        out[b] = 1.f / (1.f + expf(-pred));
    }
}

extern "C" void kernel_launch(void* const* d_in, const int* in_sizes, int n_in,
                              void* d_out, int out_size, void* d_ws, size_t ws_size,
                              hipStream_t stream) {
    const int*   history        = (const int*)  d_in[0];
    const int*   target         = (const int*)  d_in[1];
    const int*   history_region = (const int*)  d_in[2];
    const int*   target_region  = (const int*)  d_in[3];
    const float* W_hist         = (const float*)d_in[4];
    const float* W_tgt          = (const float*)d_in[5];
    const float* W_reg          = (const float*)d_in[6];
    const float* W1             = (const float*)d_in[7];
    const float* b1             = (const float*)d_in[8];
    const float* W2             = (const float*)d_in[9];
    float* out = (float*)d_out;

    const size_t need = (size_t)(HIST_ROWS + REG_ROWS) * 64 * 2;   // 12.93 MB
    if (ws_size >= need) {
        unsigned short* tab = (unsigned short*)d_ws;
        cvt_tables<<<2048, 256, 0, stream>>>(W_hist, W_reg, tab);
        nais_mfma3<true><<<NB, 256, 0, stream>>>(history, target, history_region, target_region,
                                                 W_hist, W_tgt, W_reg, W1, b1, W2, tab, out);
    } else {
        nais_mfma3<false><<<NB, 256, 0, stream>>>(history, target, history_region, target_region,
                                                  W_hist, W_tgt, W_reg, W1, b1, W2, nullptr, out);
    }
}